// Round 1
// baseline (25369.792 us; speedup 1.0000x reference)
//
#include <hip/hip_runtime.h>
#include <math.h>

#define M_DIM 4096
#define T_X   128
#define NV    256
#define NA    512
#define NG    2048   // 4*NA
#define KT    768    // NV + NA

__device__ __forceinline__ float sigm(float x) { return 1.0f / (1.0f + expf(-x)); }

// Build Wt[768][2048] (column-major view of stacked [W_ih; W_hh]), bias sum,
// WtO[512][256] (W_out^T), and initialize h0 = a0, c = c0.
__global__ void prep_kernel(const float* __restrict__ a0, const float* __restrict__ c0,
                            const float* __restrict__ W_ih, const float* __restrict__ W_hh,
                            const float* __restrict__ b_ih, const float* __restrict__ b_hh,
                            const float* __restrict__ W_out,
                            float* __restrict__ h0, float* __restrict__ c,
                            float* __restrict__ Wt, float* __restrict__ bs,
                            float* __restrict__ WtO)
{
    const int NTOT = KT*NG + NG + NA*NV + M_DIM*NA;
    for (int idx = blockIdx.x * blockDim.x + threadIdx.x; idx < NTOT;
         idx += gridDim.x * blockDim.x) {
        int i = idx;
        if (i < KT*NG) {
            int k = i / NG, n = i % NG;
            Wt[i] = (k < NV) ? W_ih[n*NV + k] : W_hh[n*NA + (k - NV)];
            continue;
        }
        i -= KT*NG;
        if (i < NG) { bs[i] = b_ih[i] + b_hh[i]; continue; }
        i -= NG;
        if (i < NA*NV) { int a = i / NV, v = i % NV; WtO[i] = W_out[v*NA + a]; continue; }
        i -= NA*NV;
        h0[i] = a0[i];
        c[i]  = c0[i];
    }
}

// One LSTM step: gates = [x_t, h_in] @ Wt + b; cell update; writes h_out, c.
// Workgroup: 64 rows (m) x 64 cols (j), computing all 4 gates for its tile.
// Threads 256 as 16x16; each thread: 4 rows x (4 gates x 4 j) = 64 fp32 acc.
__global__ __launch_bounds__(256)
void lstm_step(const float* __restrict__ X,     // [M][TX][NV]
               const float* __restrict__ h_in,  // [M][NA]
               float* __restrict__ h_out,       // [M][NA]
               float* __restrict__ c,           // [M][NA] in-place (thread-owned)
               const float* __restrict__ Wt,    // [KT][NG]
               const float* __restrict__ bs,    // [NG]
               int t)
{
    __shared__ float As[16][68];    // A tile [k][m], padded
    __shared__ float Bs[16][260];   // B tile [k][256 combined gate cols], padded

    const int tid = threadIdx.x;
    const int tx  = tid & 15;
    const int ty  = tid >> 4;
    const int jb  = blockIdx.x;          // 0..7  (j block of 64 within NA)
    const int m0  = blockIdx.y * 64;     // row block

    float acc[4][16];
    #pragma unroll
    for (int r = 0; r < 4; ++r)
        #pragma unroll
        for (int q = 0; q < 16; ++q) acc[r][q] = 0.0f;

    // A-load mapping: each thread loads one float4 along k
    const int mA = tid >> 2;   // 0..63
    const int kq = tid & 3;    // 0..3 (float4 index within 16-wide k tile)
    const float* Xrow = X + (size_t)(m0 + mA) * (T_X * NV) + (size_t)t * NV;
    const float* Hrow = h_in + (size_t)(m0 + mA) * NA;

    for (int kt = 0; kt < KT; kt += 16) {
        // ---- load A tile [64 m][16 k] ----
        float4 av;
        if (kt < NV) av = *(const float4*)(Xrow + kt + kq * 4);
        else         av = *(const float4*)(Hrow + (kt - NV) + kq * 4);
        As[kq*4 + 0][mA] = av.x;
        As[kq*4 + 1][mA] = av.y;
        As[kq*4 + 2][mA] = av.z;
        As[kq*4 + 3][mA] = av.w;

        // ---- load B tile [16 k][256 n] (4 gate strips of 64) ----
        #pragma unroll
        for (int i = 0; i < 4; ++i) {
            int e  = i * 256 + tid;      // float4 unit index, 0..1023
            int kk = e >> 6;             // 0..15
            int nl = (e & 63) * 4;       // 0..252
            int g  = nl >> 6;            // gate strip
            int jc = nl & 63;
            const float* src = Wt + (size_t)(kt + kk) * NG + g * NA + jb * 64 + jc;
            *(float4*)&Bs[kk][nl] = *(const float4*)src;
        }
        __syncthreads();

        #pragma unroll
        for (int kk = 0; kk < 16; ++kk) {
            float ar[4];
            *(float4*)ar = *(const float4*)&As[kk][ty * 4];
            float br[16];
            *(float4*)&br[0]  = *(const float4*)&Bs[kk][  0 + tx * 4];
            *(float4*)&br[4]  = *(const float4*)&Bs[kk][ 64 + tx * 4];
            *(float4*)&br[8]  = *(const float4*)&Bs[kk][128 + tx * 4];
            *(float4*)&br[12] = *(const float4*)&Bs[kk][192 + tx * 4];
            #pragma unroll
            for (int r = 0; r < 4; ++r)
                #pragma unroll
                for (int q = 0; q < 16; ++q)
                    acc[r][q] = fmaf(ar[r], br[q], acc[r][q]);
        }
        __syncthreads();
    }

    // ---- epilogue: bias + activations + cell update ----
    const int jcol = jb * 64 + tx * 4;
    float bb[16];
    *(float4*)&bb[0]  = *(const float4*)(bs + 0 * NA + jcol);
    *(float4*)&bb[4]  = *(const float4*)(bs + 1 * NA + jcol);
    *(float4*)&bb[8]  = *(const float4*)(bs + 2 * NA + jcol);
    *(float4*)&bb[12] = *(const float4*)(bs + 3 * NA + jcol);

    #pragma unroll
    for (int r = 0; r < 4; ++r) {
        const size_t m = (size_t)(m0 + ty * 4 + r);
        float cv[4], cn[4], hn[4];
        *(float4*)cv = *(const float4*)(c + m * NA + jcol);
        #pragma unroll
        for (int jj = 0; jj < 4; ++jj) {
            float iv = sigm(acc[r][ 0 + jj] + bb[ 0 + jj]);
            float fv = sigm(acc[r][ 4 + jj] + bb[ 4 + jj]);
            float gv = tanhf(acc[r][ 8 + jj] + bb[ 8 + jj]);
            float ov = sigm(acc[r][12 + jj] + bb[12 + jj]);
            cn[jj] = fv * cv[jj] + iv * gv;
            hn[jj] = ov * tanhf(cn[jj]);
        }
        *(float4*)(c + m * NA + jcol)     = *(const float4*)cn;
        *(float4*)(h_out + m * NA + jcol) = *(const float4*)hn;
    }
}

// out_t = h @ WtO + b_out : [4096, 256], K = 512
__global__ __launch_bounds__(256)
void out_proj(const float* __restrict__ h,     // [M][NA]
              const float* __restrict__ WtO,   // [NA][NV]
              const float* __restrict__ b_out, // [NV]
              float* __restrict__ out)         // [M][NV]
{
    __shared__ float As[16][68];
    __shared__ float Bs[16][68];

    const int tid = threadIdx.x;
    const int tx  = tid & 15;
    const int ty  = tid >> 4;
    const int nb  = blockIdx.x;        // 0..3
    const int m0  = blockIdx.y * 64;

    float acc[4][4];
    #pragma unroll
    for (int r = 0; r < 4; ++r)
        #pragma unroll
        for (int q = 0; q < 4; ++q) acc[r][q] = 0.0f;

    const int mA = tid >> 2;
    const int kq = tid & 3;
    const float* Hrow = h + (size_t)(m0 + mA) * NA;

    for (int kt = 0; kt < NA; kt += 16) {
        float4 av = *(const float4*)(Hrow + kt + kq * 4);
        As[kq*4 + 0][mA] = av.x;
        As[kq*4 + 1][mA] = av.y;
        As[kq*4 + 2][mA] = av.z;
        As[kq*4 + 3][mA] = av.w;
        {
            int kk = tid >> 4;           // 0..15
            int nl = (tid & 15) * 4;     // 0..60
            *(float4*)&Bs[kk][nl] =
                *(const float4*)(WtO + (size_t)(kt + kk) * NV + nb * 64 + nl);
        }
        __syncthreads();

        #pragma unroll
        for (int kk = 0; kk < 16; ++kk) {
            float ar[4];
            *(float4*)ar = *(const float4*)&As[kk][ty * 4];
            float br[4];
            *(float4*)br = *(const float4*)&Bs[kk][tx * 4];
            #pragma unroll
            for (int r = 0; r < 4; ++r)
                #pragma unroll
                for (int q = 0; q < 4; ++q)
                    acc[r][q] = fmaf(ar[r], br[q], acc[r][q]);
        }
        __syncthreads();
    }

    float bo[4];
    *(float4*)bo = *(const float4*)(b_out + nb * 64 + tx * 4);
    #pragma unroll
    for (int r = 0; r < 4; ++r) {
        const size_t m = (size_t)(m0 + ty * 4 + r);
        float res[4];
        #pragma unroll
        for (int q = 0; q < 4; ++q) res[q] = acc[r][q] + bo[q];
        *(float4*)(out + m * NV + nb * 64 + tx * 4) = *(const float4*)res;
    }
}

extern "C" void kernel_launch(void* const* d_in, const int* in_sizes, int n_in,
                              void* d_out, int out_size, void* d_ws, size_t ws_size,
                              hipStream_t stream) {
    const float* X     = (const float*)d_in[0];
    const float* a0    = (const float*)d_in[1];
    const float* c0    = (const float*)d_in[2];
    const float* W_ih  = (const float*)d_in[3];
    const float* W_hh  = (const float*)d_in[4];
    const float* b_ih  = (const float*)d_in[5];
    const float* b_hh  = (const float*)d_in[6];
    const float* W_out = (const float*)d_in[7];
    const float* b_out = (const float*)d_in[8];
    float* out = (float*)d_out;

    // ws layout (floats): h0, h1, c, Wt, bs, WtO  (~32 MB total)
    float* ws  = (float*)d_ws;
    float* h0  = ws;
    float* h1  = h0 + (size_t)M_DIM * NA;
    float* cbf = h1 + (size_t)M_DIM * NA;
    float* Wt  = cbf + (size_t)M_DIM * NA;
    float* bsm = Wt + (size_t)KT * NG;
    float* WtO = bsm + NG;

    {
        const int NTOT = KT*NG + NG + NA*NV + M_DIM*NA;
        int blocks = (NTOT + 255) / 256;
        prep_kernel<<<blocks, 256, 0, stream>>>(a0, c0, W_ih, W_hh, b_ih, b_hh, W_out,
                                                h0, cbf, Wt, bsm, WtO);
    }

    dim3 gridStep(NA / 64, M_DIM / 64);   // (8, 64)
    dim3 gridOut(NV / 64, M_DIM / 64);    // (4, 64)
    for (int t = 0; t < T_X; ++t) {
        const float* hi = (t & 1) ? h1 : h0;
        float*       ho = (t & 1) ? h0 : h1;
        lstm_step<<<gridStep, 256, 0, stream>>>(X, hi, ho, cbf, Wt, bsm, t);
        out_proj<<<gridOut, 256, 0, stream>>>(ho, WtO, b_out, out + (size_t)t * M_DIM * NV);
    }
}

// Round 2
// 9258.389 us; speedup vs baseline: 2.7402x; 2.7402x over previous
//
#include <hip/hip_runtime.h>
#include <math.h>

typedef __attribute__((ext_vector_type(8))) short bf16x8;
typedef __attribute__((ext_vector_type(4))) float f32x4;
typedef __attribute__((ext_vector_type(4))) unsigned int u32x4;
typedef unsigned int u32;
typedef unsigned short u16;

#define M_DIM 4096
#define T_X   128
#define NV    256
#define NA    512
#define NG    2048
#define KT_   768
#define NKT   24   // gates k-tiles of 32

// ---------- numeric helpers ----------
__device__ __forceinline__ u32 rne_bf16(u32 u) {
    return (u + 0x7fffu + ((u >> 16) & 1u)) >> 16;
}
// split x into bf16 hi (rounded) + bf16 lo (rounded residual)
__device__ __forceinline__ void split2(float x, u32& h, u32& l) {
    u32 u = __float_as_uint(x);
    h = rne_bf16(u);
    float rest = x - __uint_as_float(h << 16);   // exact (Sterbenz)
    l = rne_bf16(__float_as_uint(rest));
}
__device__ __forceinline__ u32 split_pack(float x) {
    u32 h, l; split2(x, h, l);
    return (h & 0xffffu) | (l << 16);
}
__device__ __forceinline__ float sigf(float x) {
    return 1.0f / (1.0f + __expf(-x));
}
__device__ __forceinline__ float tanh_fast(float x) {
    float t = __expf(2.0f * x);
    return (t - 1.0f) / (t + 1.0f);
}

#define GLOAD_LDS16(G, L) \
    __builtin_amdgcn_global_load_lds((const __attribute__((address_space(1))) u32*)(G), \
                                     (__attribute__((address_space(3))) u32*)(L), 16, 0, 0)

// ---------- prep: split weights into fragment-linear bf16 hi/lo ----------
// BG layout: [kt 0..23][jb 0..15][part 0..1][fn 0..7][lane 0..63][e 0..7] u16
// BO layout: [kt 0..7][nb 0..3][part 0..1][ks 0..1][fn 0..3][lane 0..63][e 0..7] u16
__global__ void prep(const float* __restrict__ a0, const float* __restrict__ c0,
                     const float* __restrict__ W_ih, const float* __restrict__ W_hh,
                     const float* __restrict__ b_ih, const float* __restrict__ b_hh,
                     const float* __restrict__ W_out,
                     u32* __restrict__ h2a, float* __restrict__ c,
                     u16* __restrict__ BG, u16* __restrict__ BO, float* __restrict__ bs)
{
    const int N1 = KT_ * NG;        // 1,572,864
    const int N2 = NA * NV;         // 131,072
    const int N3 = NG;              // 2,048
    const int N4 = M_DIM * NA;      // 2,097,152
    const int NT = N1 + N2 + N3 + N4;
    for (int idx = blockIdx.x * blockDim.x + threadIdx.x; idx < NT;
         idx += gridDim.x * blockDim.x) {
        int i = idx;
        if (i < N1) {
            int k  = i >> 11, c2 = i & 2047;
            int jb = c2 >> 7, cc = c2 & 127, g = cc >> 5, jj = cc & 31;
            int row = g * NA + jb * 32 + jj;
            float w = (k < NV) ? W_ih[row * NV + k] : W_hh[row * NA + (k - NV)];
            u32 h, l; split2(w, h, l);
            int kt = k >> 5, ksl = (k >> 3) & 3, e = k & 7;
            int fn = cc >> 4, ln = ksl * 16 + (cc & 15);
            size_t base = ((size_t)(kt * 16 + jb)) * 8192 + (size_t)(fn * 64 + ln) * 8 + e;
            BG[base]        = (u16)h;
            BG[base + 4096] = (u16)l;
            continue;
        }
        i -= N1;
        if (i < N2) {
            int k = i >> 8, n = i & 255;
            int nb = n >> 6, nl = n & 63;
            float w = W_out[n * NA + k];
            u32 h, l; split2(w, h, l);
            int kt = k >> 6, ks = (k >> 5) & 1, ksl = (k >> 3) & 3, e = k & 7;
            int fn = nl >> 4, ln = ksl * 16 + (nl & 15);
            size_t base = ((size_t)(kt * 4 + nb)) * 8192 +
                          (size_t)((ks * 4 + fn) * 64 + ln) * 8 + e;
            BO[base]        = (u16)h;
            BO[base + 4096] = (u16)l;
            continue;
        }
        i -= N2;
        if (i < N3) { bs[i] = b_ih[i] + b_hh[i]; continue; }
        i -= N3;
        h2a[i] = split_pack(a0[i]);
        c[i]   = c0[i];
    }
}

// ---------- gates + cell kernel ----------
// grid (16 jb, 32 mb), 256 threads (4 waves as 2x2). Tile: 128 rows x (4 gates x 32 j).
__global__ __launch_bounds__(256)
void gates_step(const float* __restrict__ X, const u32* __restrict__ h2_in,
                u32* __restrict__ h2_out, float* __restrict__ c,
                const u16* __restrict__ BG, const float* __restrict__ bs, int t)
{
    __shared__ char smem[65536];   // 2 x (Ah 8K | Al 8K | Bh 8K | Bl 8K); epilogue: G fp32 128x128

    const int tid  = threadIdx.x;
    const int lane = tid & 63;
    const int wv   = tid >> 6;
    const int wr   = wv >> 1, wc = wv & 1;
    const int jb   = blockIdx.x;
    const int mb   = blockIdx.y;

    f32x4 acc[4][4];
    #pragma unroll
    for (int a = 0; a < 4; ++a)
        #pragma unroll
        for (int b = 0; b < 4; ++b) acc[a][b] = (f32x4){0.f, 0.f, 0.f, 0.f};

    // A staging identity: thread -> (row r, k-half kh of 32-wide tile)
    const int r  = tid >> 1;
    const int kh = tid & 1;
    const size_t row_g = (size_t)mb * 128 + r;
    const u32* pX  = (const u32*)(X + row_g * (size_t)(T_X * NV) + (size_t)t * NV) + kh * 16;
    const u32* pH8 = h2_in + row_g * NA + kh * 16;

    u32x4 rx[4];

    auto stageB = [&](int ktn, int b) {
        const char* src = (const char*)BG + ((size_t)(ktn * 16 + jb)) * 16384
                        + (size_t)(wv * 4) * 1024 + (size_t)lane * 16;
        char* dst = smem + b * 32768 + 16384 + wv * 4 * 1024;
        #pragma unroll
        for (int i = 0; i < 4; ++i) GLOAD_LDS16(src + i * 1024, dst + i * 1024);
    };
    auto loadA = [&](int ktn) {
        const u32* p = (ktn < 8) ? (pX + ktn * 32) : (pH8 + (ktn - 8) * 32);
        #pragma unroll
        for (int i = 0; i < 4; ++i) rx[i] = *(const u32x4*)(p + i * 4);
    };
    auto writeA = [&](int ktn, int b) {
        char* base = smem + b * 32768;
        #pragma unroll
        for (int s = 0; s < 2; ++s) {
            u32 hw[4], lw[4];
            if (ktn < 8) {
                #pragma unroll
                for (int k2 = 0; k2 < 4; ++k2) {
                    u32 e0 = rx[2 * s + (k2 >> 1)][(k2 & 1) * 2 + 0];
                    u32 e1 = rx[2 * s + (k2 >> 1)][(k2 & 1) * 2 + 1];
                    u32 h0, l0, h1, l1;
                    split2(__uint_as_float(e0), h0, l0);
                    split2(__uint_as_float(e1), h1, l1);
                    hw[k2] = (h0 & 0xffffu) | (h1 << 16);
                    lw[k2] = (l0 & 0xffffu) | (l1 << 16);
                }
            } else {
                #pragma unroll
                for (int k2 = 0; k2 < 4; ++k2) {
                    u32 u0 = rx[2 * s + (k2 >> 1)][(k2 & 1) * 2 + 0];
                    u32 u1 = rx[2 * s + (k2 >> 1)][(k2 & 1) * 2 + 1];
                    hw[k2] = __builtin_amdgcn_perm(u1, u0, 0x05040100u);
                    lw[k2] = __builtin_amdgcn_perm(u1, u0, 0x07060302u);
                }
            }
            const int slot = (r >> 4) * 64 + (kh * 2 + s) * 16 + (r & 15);
            *(u32x4*)(base + slot * 16)        = (u32x4){hw[0], hw[1], hw[2], hw[3]};
            *(u32x4*)(base + 8192 + slot * 16) = (u32x4){lw[0], lw[1], lw[2], lw[3]};
        }
    };
    auto compute = [&](int b) {
        const char* base = smem + b * 32768;
        bf16x8 bh[4], bl[4];
        #pragma unroll
        for (int fn = 0; fn < 4; ++fn) {
            bh[fn] = *(const bf16x8*)(base + 16384 + ((wc * 4 + fn) * 64 + lane) * 16);
            bl[fn] = *(const bf16x8*)(base + 24576 + ((wc * 4 + fn) * 64 + lane) * 16);
        }
        #pragma unroll
        for (int fm = 0; fm < 4; ++fm) {
            bf16x8 ah = *(const bf16x8*)(base + ((wr * 4 + fm) * 64 + lane) * 16);
            bf16x8 al = *(const bf16x8*)(base + 8192 + ((wr * 4 + fm) * 64 + lane) * 16);
            #pragma unroll
            for (int fn = 0; fn < 4; ++fn) {
                acc[fm][fn] = __builtin_amdgcn_mfma_f32_16x16x32_bf16(ah, bh[fn], acc[fm][fn], 0, 0, 0);
                acc[fm][fn] = __builtin_amdgcn_mfma_f32_16x16x32_bf16(ah, bl[fn], acc[fm][fn], 0, 0, 0);
                acc[fm][fn] = __builtin_amdgcn_mfma_f32_16x16x32_bf16(al, bh[fn], acc[fm][fn], 0, 0, 0);
            }
        }
    };

    // prologue
    stageB(0, 0);
    loadA(0);
    writeA(0, 0);
    __syncthreads();

    for (int kt = 0; kt < NKT; ++kt) {
        const int cur = kt & 1;
        if (kt + 1 < NKT) { stageB(kt + 1, cur ^ 1); loadA(kt + 1); }
        compute(cur);
        if (kt + 1 < NKT) writeA(kt + 1, cur ^ 1);
        __syncthreads();
    }

    // ---- epilogue: gates -> LDS (XOR swizzle) -> cell update ----
    float* G = (float*)smem;
    #pragma unroll
    for (int fm = 0; fm < 4; ++fm)
        #pragma unroll
        for (int fn = 0; fn < 4; ++fn)
            #pragma unroll
            for (int q = 0; q < 4; ++q) {
                int row_t = wr * 64 + fm * 16 + (lane >> 4) * 4 + q;
                int col_t = wc * 64 + fn * 16 + (lane & 15);
                int col_s = col_t ^ (((row_t >> 2) & 7) << 2);
                G[row_t * 128 + col_s] = acc[fm][fn][q];
            }
    __syncthreads();

    const int jj = tid & 31;
    const int rb = tid >> 5;
    const int col_g = jb * 32 + jj;
    const float bsi = bs[col_g], bsf = bs[NA + col_g];
    const float bsg = bs[2 * NA + col_g], bso = bs[3 * NA + col_g];
    #pragma unroll
    for (int rr = 0; rr < 16; ++rr) {
        int row_t = rb * 16 + rr;
        int sw = ((row_t >> 2) & 7) << 2;
        float gi = G[row_t * 128 + ((0   + jj) ^ sw)] + bsi;
        float gf = G[row_t * 128 + ((32  + jj) ^ sw)] + bsf;
        float gg = G[row_t * 128 + ((64  + jj) ^ sw)] + bsg;
        float go = G[row_t * 128 + ((96  + jj) ^ sw)] + bso;
        size_t m = (size_t)mb * 128 + row_t;
        float cv = c[m * NA + col_g];
        float iv = sigf(gi), fv = sigf(gf);
        float gv = tanh_fast(gg), ov = sigf(go);
        float cn = fv * cv + iv * gv;
        float hn = ov * tanh_fast(cn);
        c[m * NA + col_g]      = cn;
        h2_out[m * NA + col_g] = split_pack(hn);
    }
}

// ---------- output projection: out = h @ W_out^T + b_out ----------
// grid (4 nb, 32 mb), 256 threads (4 waves as 2x2). Tile 128 x 64, K=512, BK=64.
__global__ __launch_bounds__(256)
void out_proj(const u32* __restrict__ h2, const u16* __restrict__ BO,
              const float* __restrict__ b_out, float* __restrict__ out)
{
    __shared__ char smem[49152];   // Ah 16K | Al 16K | Bh 8K | Bl 8K

    const int tid  = threadIdx.x;
    const int lane = tid & 63;
    const int wv   = tid >> 6;
    const int wr   = wv >> 1, wc = wv & 1;
    const int nb   = blockIdx.x;
    const int mb   = blockIdx.y;

    f32x4 acc[4][2];
    #pragma unroll
    for (int a = 0; a < 4; ++a) { acc[a][0] = (f32x4){0,0,0,0}; acc[a][1] = (f32x4){0,0,0,0}; }

    const int r  = tid >> 1;
    const int kh = tid & 1;   // which 32-k half of BK=64
    const size_t row_g = (size_t)mb * 128 + r;
    const u32* pH = h2 + row_g * NA + kh * 32;

    for (int kt = 0; kt < 8; ++kt) {
        __syncthreads();
        // B: 16KB chunk
        {
            const char* src = (const char*)BO + ((size_t)(kt * 4 + nb)) * 16384
                            + (size_t)(wv * 4) * 1024 + (size_t)lane * 16;
            char* dst = smem + 32768 + wv * 4 * 1024;
            #pragma unroll
            for (int i = 0; i < 4; ++i) GLOAD_LDS16(src + i * 1024, dst + i * 1024);
        }
        // A: 32 packed u32 per thread
        u32x4 rh[8];
        {
            const u32x4* q = (const u32x4*)(pH + kt * 64);
            #pragma unroll
            for (int i = 0; i < 8; ++i) rh[i] = q[i];
        }
        #pragma unroll
        for (int ss = 0; ss < 4; ++ss) {
            u32 hw[4], lw[4];
            #pragma unroll
            for (int k2 = 0; k2 < 4; ++k2) {
                u32 u0 = rh[ss * 2 + (k2 >> 1)][(k2 & 1) * 2 + 0];
                u32 u1 = rh[ss * 2 + (k2 >> 1)][(k2 & 1) * 2 + 1];
                hw[k2] = __builtin_amdgcn_perm(u1, u0, 0x05040100u);
                lw[k2] = __builtin_amdgcn_perm(u1, u0, 0x07060302u);
            }
            const int slot = ((r >> 4) * 2 + kh) * 64 + ss * 16 + (r & 15);
            *(u32x4*)(smem + slot * 16)         = (u32x4){hw[0], hw[1], hw[2], hw[3]};
            *(u32x4*)(smem + 16384 + slot * 16) = (u32x4){lw[0], lw[1], lw[2], lw[3]};
        }
        __syncthreads();
        #pragma unroll
        for (int ks = 0; ks < 2; ++ks) {
            bf16x8 bh[2], bl[2];
            #pragma unroll
            for (int fq = 0; fq < 2; ++fq) {
                int fn = wc * 2 + fq;
                bh[fq] = *(const bf16x8*)(smem + 32768 + ((ks * 4 + fn) * 64 + lane) * 16);
                bl[fq] = *(const bf16x8*)(smem + 40960 + ((ks * 4 + fn) * 64 + lane) * 16);
            }
            #pragma unroll
            for (int fm = 0; fm < 4; ++fm) {
                int mf = wr * 4 + fm;
                bf16x8 ah = *(const bf16x8*)(smem + ((mf * 2 + ks) * 64 + lane) * 16);
                bf16x8 al = *(const bf16x8*)(smem + 16384 + ((mf * 2 + ks) * 64 + lane) * 16);
                #pragma unroll
                for (int fq = 0; fq < 2; ++fq) {
                    acc[fm][fq] = __builtin_amdgcn_mfma_f32_16x16x32_bf16(ah, bh[fq], acc[fm][fq], 0, 0, 0);
                    acc[fm][fq] = __builtin_amdgcn_mfma_f32_16x16x32_bf16(ah, bl[fq], acc[fm][fq], 0, 0, 0);
                    acc[fm][fq] = __builtin_amdgcn_mfma_f32_16x16x32_bf16(al, bh[fq], acc[fm][fq], 0, 0, 0);
                }
            }
        }
    }

    const float bo0 = b_out[nb * 64 + wc * 32 + (lane & 15)];
    const float bo1 = b_out[nb * 64 + wc * 32 + 16 + (lane & 15)];
    #pragma unroll
    for (int fm = 0; fm < 4; ++fm)
        #pragma unroll
        for (int fq = 0; fq < 2; ++fq)
            #pragma unroll
            for (int q = 0; q < 4; ++q) {
                int row_t = wr * 64 + fm * 16 + (lane >> 4) * 4 + q;
                int col   = nb * 64 + wc * 32 + fq * 16 + (lane & 15);
                out[((size_t)mb * 128 + row_t) * NV + col] = acc[fm][fq][q] + (fq ? bo1 : bo0);
            }
}

// ---------- host ----------
extern "C" void kernel_launch(void* const* d_in, const int* in_sizes, int n_in,
                              void* d_out, int out_size, void* d_ws, size_t ws_size,
                              hipStream_t stream) {
    const float* X     = (const float*)d_in[0];
    const float* a0    = (const float*)d_in[1];
    const float* c0    = (const float*)d_in[2];
    const float* W_ih  = (const float*)d_in[3];
    const float* W_hh  = (const float*)d_in[4];
    const float* b_ih  = (const float*)d_in[5];
    const float* b_hh  = (const float*)d_in[6];
    const float* W_out = (const float*)d_in[7];
    const float* b_out = (const float*)d_in[8];
    float* out = (float*)d_out;

    char* w = (char*)d_ws;
    u32*   h2a = (u32*)(w);
    u32*   h2b = (u32*)(w + ((size_t)8 << 20));
    float* cbf = (float*)(w + ((size_t)16 << 20));
    u16*   BG  = (u16*)(w + ((size_t)24 << 20));                  // 6,291,456 B
    u16*   BO  = (u16*)(w + ((size_t)24 << 20) + 6291456);        // 524,288 B
    float* bs  = (float*)(w + ((size_t)24 << 20) + 6291456 + 524288);

    prep<<<8192, 256, 0, stream>>>(a0, c0, W_ih, W_hh, b_ih, b_hh, W_out,
                                   h2a, cbf, BG, BO, bs);

    dim3 gGates(16, 32);
    dim3 gOut(4, 32);
    for (int t = 0; t < T_X; ++t) {
        const u32* hi = (t & 1) ? h2b : h2a;
        u32*       ho = (t & 1) ? h2a : h2b;
        gates_step<<<gGates, 256, 0, stream>>>(X, hi, ho, cbf, BG, bs, t);
        out_proj<<<gOut, 256, 0, stream>>>(ho, BO, b_out, out + (size_t)t * M_DIM * NV);
    }
}

// Round 3
// 4481.704 us; speedup vs baseline: 5.6607x; 2.0658x over previous
//
#include <hip/hip_runtime.h>
#include <math.h>

typedef _Float16 f16;
typedef _Float16 f16x8 __attribute__((ext_vector_type(8)));
typedef float f32x4 __attribute__((ext_vector_type(4)));
typedef unsigned int u32;
typedef unsigned short u16;

#define M_DIM 4096
#define T_X   128
#define NV    256
#define NA    512
#define NG    2048
#define KT_   768
#define NKT   24   // gates k-tiles of 32

__device__ __forceinline__ float sigf(float x) { return 1.0f / (1.0f + __expf(-x)); }
__device__ __forceinline__ float tanh_fast(float x) {
    float t = __expf(2.0f * x);
    return (t - 1.0f) / (t + 1.0f);
}

#define GLOAD_LDS16(G, L) \
    __builtin_amdgcn_global_load_lds((const __attribute__((address_space(1))) u32*)(G), \
                                     (__attribute__((address_space(3))) u32*)(L), 16, 0, 0)

// ============================ prep =============================
// BG: [kt 24][jb 16] tiles of 4096 u16: frag f = wcc*4+g, [f][lane 64][e 8]
//     n = g*512 + jb*32 + wcc*16 + (lane&15); k = kt*32 + (lane>>4)*8 + e
// BO: [kt 16][nb 4] tiles of 2048 u16: frag f 0..3, n = nb*64 + f*16 + (lane&15)
// Hf: [mb 32][kt 16] tiles of 4096 u16: [mf 8][lane 64][e 8]
//     m = mb*128 + mf*16 + (lane&15); k = kt*32 + (lane>>4)*8 + e
__global__ void prep(const float* __restrict__ a0, const float* __restrict__ c0,
                     const float* __restrict__ W_ih, const float* __restrict__ W_hh,
                     const float* __restrict__ b_ih, const float* __restrict__ b_hh,
                     const float* __restrict__ W_out,
                     u16* __restrict__ Ha, float* __restrict__ c,
                     u16* __restrict__ BG, u16* __restrict__ BO, float* __restrict__ bs)
{
    const int N_BG = NKT * 16 * 4096;   // 1,572,864
    const int N_BO = 16 * 4 * 2048;     // 131,072
    const int N_BS = NG;                // 2,048
    const int N_H  = 32 * 16 * 4096;    // 2,097,152
    const int N_C  = M_DIM * NA;        // 2,097,152
    const int NT = N_BG + N_BO + N_BS + N_H + N_C;
    for (int idx = blockIdx.x * blockDim.x + threadIdx.x; idx < NT;
         idx += gridDim.x * blockDim.x) {
        int i = idx;
        if (i < N_BG) {
            int tile = i >> 12, w = i & 4095;
            int jb = tile & 15, kt = tile >> 4;
            int f = w >> 9, lane = (w >> 3) & 63, e = w & 7;
            int wcc = f >> 2, g = f & 3;
            int n = g * NA + jb * 32 + wcc * 16 + (lane & 15);
            int k = kt * 32 + ((lane >> 4) << 3) + e;
            float v = (k < NV) ? W_ih[n * NV + k] : W_hh[n * NA + (k - NV)];
            BG[i] = __builtin_bit_cast(u16, (f16)v);
            continue;
        }
        i -= N_BG;
        if (i < N_BO) {
            int tile = i >> 11, w = i & 2047;
            int nb = tile & 3, kt = tile >> 2;
            int f = w >> 9, lane = (w >> 3) & 63, e = w & 7;
            int n = nb * 64 + f * 16 + (lane & 15);
            int k = kt * 32 + ((lane >> 4) << 3) + e;
            BO[i] = __builtin_bit_cast(u16, (f16)W_out[n * NA + k]);
            continue;
        }
        i -= N_BO;
        if (i < N_BS) { bs[i] = b_ih[i] + b_hh[i]; continue; }
        i -= N_BS;
        if (i < N_H) {
            int tile = i >> 12, w = i & 4095;
            int kt = tile & 15, mb = tile >> 4;
            int mf = w >> 9, lane = (w >> 3) & 63, e = w & 7;
            int m = mb * 128 + mf * 16 + (lane & 15);
            int k = kt * 32 + ((lane >> 4) << 3) + e;
            Ha[i] = __builtin_bit_cast(u16, (f16)a0[m * NA + k]);
            continue;
        }
        i -= N_H;
        c[i] = c0[i];
    }
}

// ====================== gates + cell step ======================
// grid 512 (decoded: all 16 jb of an mb on one XCD), 256 threads, 4 waves 2x2.
// Block tile: 128 m x (4 gates x 32 j). LDS: 2 x (A 8K | B 8K) = 32 KB.
__global__ __launch_bounds__(256)
void gates_step(const float* __restrict__ X, const u16* __restrict__ Hin,
                u16* __restrict__ Hout, float* __restrict__ c,
                const u16* __restrict__ BG, const float* __restrict__ bs, int t)
{
    __shared__ char smem[32768];

    const int id  = blockIdx.x;
    const int xcd = id & 7, g2 = id >> 3;
    const int jb  = g2 & 15;
    const int mb  = xcd + 8 * (g2 >> 4);

    const int tid = threadIdx.x, lane = tid & 63, wv = tid >> 6;
    const int wr = wv >> 1, wc = wv & 1;

    f32x4 acc[4][4];
    #pragma unroll
    for (int a = 0; a < 4; ++a)
        #pragma unroll
        for (int b = 0; b < 4; ++b) acc[a][b] = (f32x4){0.f, 0.f, 0.f, 0.f};

    // X convert-path mapping: thread -> (row r, k-half kh)
    const int r  = tid >> 1;
    const int kh = tid & 1;
    const float* Xrow = X + ((size_t)(mb * 128 + r) * T_X + t) * NV + kh * 16;

    f32x4 xr[4];

    auto stage_dma = [&](int ktn, int buf) {
        char* base = smem + buf * 16384;
        if (ktn >= 8) {
            const char* asrc = (const char*)(Hin + ((size_t)(mb * 16 + (ktn - 8))) * 4096);
            GLOAD_LDS16(asrc + wv * 2048 + lane * 16,        base + wv * 2048);
            GLOAD_LDS16(asrc + wv * 2048 + 1024 + lane * 16, base + wv * 2048 + 1024);
        }
        const char* bsrc = (const char*)(BG + ((size_t)(ktn * 16 + jb)) * 4096);
        GLOAD_LDS16(bsrc + wv * 2048 + lane * 16,        base + 8192 + wv * 2048);
        GLOAD_LDS16(bsrc + wv * 2048 + 1024 + lane * 16, base + 8192 + wv * 2048 + 1024);
    };
    auto loadX = [&](int ktn) {
        const f32x4* p = (const f32x4*)(Xrow + ktn * 32);
        #pragma unroll
        for (int i = 0; i < 4; ++i) xr[i] = p[i];
    };
    auto writeX = [&](int buf) {
        char* base = smem + buf * 16384;
        const int mf = r >> 4;
        #pragma unroll
        for (int s = 0; s < 2; ++s) {
            f16x8 v;
            #pragma unroll
            for (int j = 0; j < 8; ++j) v[j] = (f16)xr[s * 2 + (j >> 2)][j & 3];
            const int lanep = (r & 15) + 16 * (kh * 2 + s);
            *(f16x8*)(base + ((mf * 64 + lanep) << 4)) = v;
        }
    };
    auto compute = [&](int buf) {
        const char* base = smem + buf * 16384;
        f16x8 bfr[4];
        #pragma unroll
        for (int g = 0; g < 4; ++g)
            bfr[g] = *(const f16x8*)(base + 8192 + (((wc * 4 + g) * 64 + lane) << 4));
        #pragma unroll
        for (int fm = 0; fm < 4; ++fm) {
            f16x8 af = *(const f16x8*)(base + (((wr * 4 + fm) * 64 + lane) << 4));
            #pragma unroll
            for (int g = 0; g < 4; ++g)
                acc[fm][g] = __builtin_amdgcn_mfma_f32_16x16x32_f16(af, bfr[g], acc[fm][g], 0, 0, 0);
        }
    };

    // prologue: tile 0 (X path)
    loadX(0);
    stage_dma(0, 0);
    writeX(0);
    __syncthreads();

    for (int kt = 0; kt < NKT; ++kt) {
        const int cur = kt & 1;
        if (kt + 1 < NKT) {
            stage_dma(kt + 1, cur ^ 1);
            if (kt + 1 < 8) loadX(kt + 1);
        }
        compute(cur);
        if (kt + 1 < 8) writeX(cur ^ 1);
        __syncthreads();
    }

    // ---- epilogue: bias + activations + cell update + fragment-linear h store ----
    const int ll = lane & 15, lh = lane >> 4;
    const int colg = jb * 32 + wc * 16 + ll;
    float bsv[4];
    #pragma unroll
    for (int g = 0; g < 4; ++g) bsv[g] = bs[g * NA + colg];

    u16* htile = Hout + ((size_t)(mb * 16 + jb)) * 4096;
    const int ksub = wc * 2 + (ll >> 3);
    const int e = ll & 7;

    #pragma unroll
    for (int fm = 0; fm < 4; ++fm) {
        const int mf = wr * 4 + fm;
        #pragma unroll
        for (int q = 0; q < 4; ++q) {
            const int rloc = mf * 16 + lh * 4 + q;
            const size_t m = (size_t)mb * 128 + rloc;
            float gi = acc[fm][0][q] + bsv[0];
            float gf = acc[fm][1][q] + bsv[1];
            float gg = acc[fm][2][q] + bsv[2];
            float go = acc[fm][3][q] + bsv[3];
            float cv = c[m * NA + colg];
            float iv = sigf(gi), fv = sigf(gf);
            float gv = tanh_fast(gg), ov = sigf(go);
            float cn = fv * cv + iv * gv;
            float hn = ov * tanh_fast(cn);
            c[m * NA + colg] = cn;
            const int lanep = (lh * 4 + q) + 16 * ksub;
            htile[(mf * 64 + lanep) * 8 + e] = __builtin_bit_cast(u16, (f16)hn);
        }
    }
}

// ====================== output projection ======================
// grid 128, 256 threads, 4 waves 2x2. Tile 128 m x 64 n, K=512, BK=32.
__global__ __launch_bounds__(256)
void out_proj(const u16* __restrict__ Hin, const u16* __restrict__ BO,
              const float* __restrict__ b_out, float* __restrict__ out)
{
    __shared__ char smem[24576];   // 2 x (A 8K | B 4K)

    const int id  = blockIdx.x;
    const int xcd = id & 7, g2 = id >> 3;
    const int nb  = g2 & 3;
    const int mb  = xcd + 8 * (g2 >> 2);

    const int tid = threadIdx.x, lane = tid & 63, wv = tid >> 6;
    const int wr = wv >> 1, wc = wv & 1;

    f32x4 acc[4][2];
    #pragma unroll
    for (int a = 0; a < 4; ++a) { acc[a][0] = (f32x4){0,0,0,0}; acc[a][1] = (f32x4){0,0,0,0}; }

    auto stage = [&](int kt, int buf) {
        char* base = smem + buf * 12288;
        const char* asrc = (const char*)(Hin + ((size_t)(mb * 16 + kt)) * 4096);
        GLOAD_LDS16(asrc + wv * 2048 + lane * 16,        base + wv * 2048);
        GLOAD_LDS16(asrc + wv * 2048 + 1024 + lane * 16, base + wv * 2048 + 1024);
        const char* bsrc = (const char*)(BO + ((size_t)(kt * 4 + nb)) * 2048);
        GLOAD_LDS16(bsrc + wv * 1024 + lane * 16, base + 8192 + wv * 1024);
    };
    auto compute = [&](int buf) {
        const char* base = smem + buf * 12288;
        f16x8 bfr[2];
        #pragma unroll
        for (int fq = 0; fq < 2; ++fq)
            bfr[fq] = *(const f16x8*)(base + 8192 + (((wc * 2 + fq) * 64 + lane) << 4));
        #pragma unroll
        for (int fm = 0; fm < 4; ++fm) {
            f16x8 af = *(const f16x8*)(base + (((wr * 4 + fm) * 64 + lane) << 4));
            #pragma unroll
            for (int fq = 0; fq < 2; ++fq)
                acc[fm][fq] = __builtin_amdgcn_mfma_f32_16x16x32_f16(af, bfr[fq], acc[fm][fq], 0, 0, 0);
        }
    };

    stage(0, 0);
    __syncthreads();
    for (int kt = 0; kt < 16; ++kt) {
        const int cur = kt & 1;
        if (kt + 1 < 16) stage(kt + 1, cur ^ 1);
        compute(cur);
        __syncthreads();
    }

    const int ll = lane & 15, lh = lane >> 4;
    float bov[2];
    #pragma unroll
    for (int fq = 0; fq < 2; ++fq) bov[fq] = b_out[nb * 64 + (wc * 2 + fq) * 16 + ll];

    #pragma unroll
    for (int fm = 0; fm < 4; ++fm)
        #pragma unroll
        for (int fq = 0; fq < 2; ++fq)
            #pragma unroll
            for (int q = 0; q < 4; ++q) {
                const int row = mb * 128 + wr * 64 + fm * 16 + lh * 4 + q;
                const int col = nb * 64 + (wc * 2 + fq) * 16 + ll;
                out[(size_t)row * NV + col] = acc[fm][fq][q] + bov[fq];
            }
}

// ============================ host =============================
extern "C" void kernel_launch(void* const* d_in, const int* in_sizes, int n_in,
                              void* d_out, int out_size, void* d_ws, size_t ws_size,
                              hipStream_t stream) {
    const float* X     = (const float*)d_in[0];
    const float* a0    = (const float*)d_in[1];
    const float* c0    = (const float*)d_in[2];
    const float* W_ih  = (const float*)d_in[3];
    const float* W_hh  = (const float*)d_in[4];
    const float* b_ih  = (const float*)d_in[5];
    const float* b_hh  = (const float*)d_in[6];
    const float* W_out = (const float*)d_in[7];
    const float* b_out = (const float*)d_in[8];
    float* out = (float*)d_out;

    char* w = (char*)d_ws;
    u16*   Ha  = (u16*)(w);                                    // 4 MB
    u16*   Hb  = (u16*)(w + ((size_t)4 << 20));                // 4 MB
    float* cbf = (float*)(w + ((size_t)8 << 20));              // 8 MB
    u16*   BG  = (u16*)(w + ((size_t)16 << 20));               // 3 MB
    u16*   BO  = (u16*)(w + ((size_t)19 << 20));               // 256 KB
    float* bsv = (float*)(w + ((size_t)19 << 20) + 262144);    // 8 KB

    prep<<<8192, 256, 0, stream>>>(a0, c0, W_ih, W_hh, b_ih, b_hh, W_out,
                                   Ha, cbf, BG, BO, bsv);

    for (int t = 0; t < T_X; ++t) {
        const u16* hi = (t & 1) ? Hb : Ha;
        u16*       ho = (t & 1) ? Ha : Hb;
        gates_step<<<512, 256, 0, stream>>>(X, hi, ho, cbf, BG, bsv, t);
        out_proj<<<128, 256, 0, stream>>>(ho, BO, b_out, out + (size_t)t * M_DIM * NV);
    }
}

// Round 4
// 3539.317 us; speedup vs baseline: 7.1680x; 1.2663x over previous
//
#include <hip/hip_runtime.h>
#include <math.h>

typedef _Float16 f16;
typedef _Float16 f16x8 __attribute__((ext_vector_type(8)));
typedef float f32x4 __attribute__((ext_vector_type(4)));
typedef unsigned int u32;
typedef unsigned short u16;

#define M_DIM 4096
#define T_X   128
#define NV    256
#define NA    512
#define NG    2048
#define NKT   24   // gates k-tiles of 32 (8 X-tiles + 16 h-tiles)

__device__ __forceinline__ float sigf(float x) { return 1.0f / (1.0f + __expf(-x)); }
__device__ __forceinline__ float tanh_fast(float x) {
    float t = __expf(2.0f * x);
    return (t - 1.0f) / (t + 1.0f);
}

#define GLOAD_LDS16(G, L) \
    __builtin_amdgcn_global_load_lds((const __attribute__((address_space(1))) u32*)(G), \
                                     (__attribute__((address_space(3))) u32*)(L), 16, 0, 0)

// ============================ prep =============================
// BG : [kt 24][jb 16] tiles 4096 u16, frag f=wcc*4+g: n = g*512+jb*32+wcc*16+(l&15), k = kt*32+(l>>4)*8+e
// BOs: [kt 16][s 16] strips 512 u16: n = s*16+(l&15), k = kt*32+(l>>4)*8+e   (fused out-proj)
// BOo: [kt 16][nb 4] tiles 2048 u16 (final out_proj kernel)
// Ha : [mb 32][kt 16] tiles 4096 u16 fragment-linear h
// Xf0: [mb 32][kt 8]  tiles 4096 u16 fragment-linear x_{t=0}
__global__ void prep(const float* __restrict__ X,
                     const float* __restrict__ a0, const float* __restrict__ c0,
                     const float* __restrict__ W_ih, const float* __restrict__ W_hh,
                     const float* __restrict__ b_ih, const float* __restrict__ b_hh,
                     const float* __restrict__ W_out,
                     u16* __restrict__ Ha, float* __restrict__ c,
                     u16* __restrict__ BG, u16* __restrict__ BOs, u16* __restrict__ BOo,
                     float* __restrict__ bs, u16* __restrict__ Xf0)
{
    const int N_BG  = NKT * 16 * 4096;   // 1,572,864
    const int N_BOS = 16 * 16 * 512;     // 131,072
    const int N_BOO = 16 * 4 * 2048;     // 131,072
    const int N_BS  = NG;                // 2,048
    const int N_H   = 32 * 16 * 4096;    // 2,097,152
    const int N_XF  = 32 * 8 * 4096;     // 1,048,576
    const int N_C   = M_DIM * NA;        // 2,097,152
    const int NT = N_BG + N_BOS + N_BOO + N_BS + N_H + N_XF + N_C;
    for (int idx = blockIdx.x * blockDim.x + threadIdx.x; idx < NT;
         idx += gridDim.x * blockDim.x) {
        int i = idx;
        if (i < N_BG) {
            int tile = i >> 12, w = i & 4095;
            int jb = tile & 15, kt = tile >> 4;
            int f = w >> 9, lane = (w >> 3) & 63, e = w & 7;
            int wcc = f >> 2, g = f & 3;
            int n = g * NA + jb * 32 + wcc * 16 + (lane & 15);
            int k = kt * 32 + ((lane >> 4) << 3) + e;
            float v = (k < NV) ? W_ih[n * NV + k] : W_hh[n * NA + (k - NV)];
            BG[i] = __builtin_bit_cast(u16, (f16)v);
            continue;
        }
        i -= N_BG;
        if (i < N_BOS) {
            int tile = i >> 9, w = i & 511;
            int s = tile & 15, kt = tile >> 4;
            int lane = w >> 3, e = w & 7;
            int n = s * 16 + (lane & 15);
            int k = kt * 32 + ((lane >> 4) << 3) + e;
            BOs[i] = __builtin_bit_cast(u16, (f16)W_out[n * NA + k]);
            continue;
        }
        i -= N_BOS;
        if (i < N_BOO) {
            int tile = i >> 11, w = i & 2047;
            int nb = tile & 3, kt = tile >> 2;
            int f = w >> 9, lane = (w >> 3) & 63, e = w & 7;
            int n = nb * 64 + f * 16 + (lane & 15);
            int k = kt * 32 + ((lane >> 4) << 3) + e;
            BOo[i] = __builtin_bit_cast(u16, (f16)W_out[n * NA + k]);
            continue;
        }
        i -= N_BOO;
        if (i < N_BS) { bs[i] = b_ih[i] + b_hh[i]; continue; }
        i -= N_BS;
        if (i < N_H) {
            int tile = i >> 12, w = i & 4095;
            int kt = tile & 15, mb = tile >> 4;
            int mf = w >> 9, lane = (w >> 3) & 63, e = w & 7;
            int m = mb * 128 + mf * 16 + (lane & 15);
            int k = kt * 32 + ((lane >> 4) << 3) + e;
            Ha[i] = __builtin_bit_cast(u16, (f16)a0[m * NA + k]);
            continue;
        }
        i -= N_H;
        if (i < N_XF) {
            int tile = i >> 12, w = i & 4095;
            int kt = tile & 7, mb = tile >> 3;
            int mf = w >> 9, lane = (w >> 3) & 63, e = w & 7;
            int m = mb * 128 + mf * 16 + (lane & 15);
            int k = kt * 32 + ((lane >> 4) << 3) + e;
            Xf0[i] = __builtin_bit_cast(u16, (f16)X[(size_t)m * (T_X * NV) + k]);
            continue;
        }
        i -= N_XF;
        c[i] = c0[i];
    }
}

// ====================== fused step kernel ======================
// Computes: gates_t + cell update + h_t  AND  out_{t-1} = h_{t-1} @ W_out^T + b_out
// AND converts X[:, t+1, :] -> fragment-linear fp16 for the next step.
// grid 512 (XCD-swizzled), 256 threads = 4 waves (2x2).
// LDS: 3 x 16KB pipeline bufs + 16KB BO strips = 64KB.
__global__ __launch_bounds__(256)
void step_fused(const float* __restrict__ X,
                const u16* __restrict__ Xf_cur, u16* __restrict__ Xf_next,
                const u16* __restrict__ Hin, u16* __restrict__ Hout,
                float* __restrict__ c,
                const u16* __restrict__ BG, const u16* __restrict__ BOs,
                const float* __restrict__ bs, const float* __restrict__ b_out,
                float* __restrict__ out_prev, int t, int do_out, int do_xconv)
{
    __shared__ char smem[65536];
    char* BO_lds = smem + 49152;

    const int id  = blockIdx.x;
    const int xcd = id & 7, g2 = id >> 3;
    const int jb  = g2 & 15;
    const int mb  = xcd + 8 * (g2 >> 4);

    const int tid = threadIdx.x, lane = tid & 63, wv = tid >> 6;
    const int wr = wv >> 1, wc = wv & 1;

    f32x4 acc[4][4];
    #pragma unroll
    for (int a = 0; a < 4; ++a)
        #pragma unroll
        for (int b = 0; b < 4; ++b) acc[a][b] = (f32x4){0.f, 0.f, 0.f, 0.f};
    f32x4 acc_o[4];
    #pragma unroll
    for (int a = 0; a < 4; ++a) acc_o[a] = (f32x4){0.f, 0.f, 0.f, 0.f};

    auto stage = [&](int ktn, int buf) {
        char* base = smem + buf * 16384;
        const char* asrc = (ktn < 8)
            ? (const char*)(Xf_cur + ((size_t)(mb * 8 + ktn)) * 4096)
            : (const char*)(Hin + ((size_t)(mb * 16 + (ktn - 8))) * 4096);
        GLOAD_LDS16(asrc + wv * 2048 + lane * 16,        base + wv * 2048);
        GLOAD_LDS16(asrc + wv * 2048 + 1024 + lane * 16, base + wv * 2048 + 1024);
        const char* bsrc = (const char*)(BG + ((size_t)(ktn * 16 + jb)) * 4096);
        GLOAD_LDS16(bsrc + wv * 2048 + lane * 16,        base + 8192 + wv * 2048);
        GLOAD_LDS16(bsrc + wv * 2048 + 1024 + lane * 16, base + 8192 + wv * 2048 + 1024);
    };
    auto compute = [&](int ktn, int buf) {
        const char* base = smem + buf * 16384;
        f16x8 af[4], bfr[4];
        #pragma unroll
        for (int g = 0; g < 4; ++g)
            bfr[g] = *(const f16x8*)(base + 8192 + (((wc * 4 + g) * 64 + lane) << 4));
        #pragma unroll
        for (int fm = 0; fm < 4; ++fm)
            af[fm] = *(const f16x8*)(base + (((wr * 4 + fm) * 64 + lane) << 4));
        #pragma unroll
        for (int fm = 0; fm < 4; ++fm)
            #pragma unroll
            for (int g = 0; g < 4; ++g)
                acc[fm][g] = __builtin_amdgcn_mfma_f32_16x16x32_f16(af[fm], bfr[g], acc[fm][g], 0, 0, 0);
        if (do_out && ktn >= 8 && ((ktn - 8) & 1) == wc) {
            f16x8 bo = *(const f16x8*)(BO_lds + (ktn - 8) * 1024 + lane * 16);
            #pragma unroll
            for (int fm = 0; fm < 4; ++fm)
                acc_o[fm] = __builtin_amdgcn_mfma_f32_16x16x32_f16(af[fm], bo, acc_o[fm], 0, 0, 0);
        }
    };

    // prologue: BO strips (one-time) + first two pipeline stages
    #pragma unroll
    for (int i = 0; i < 4; ++i) {
        int kt = wv * 4 + i;
        const char* src = (const char*)(BOs + ((size_t)(kt * 16 + jb)) * 512);
        GLOAD_LDS16(src + lane * 16, BO_lds + kt * 1024);
    }
    stage(0, 0);
    stage(1, 1);

    // main loop: 1 barrier + counted vmcnt per tile; loads span barriers
    int cur = 0;
    for (int kt = 0; kt < NKT - 1; ++kt) {
        asm volatile("s_waitcnt vmcnt(4)" ::: "memory");
        __builtin_amdgcn_s_barrier();
        if (kt + 2 < NKT) {
            int stb = cur + 2; if (stb >= 3) stb -= 3;
            stage(kt + 2, stb);
        }
        compute(kt, cur);
        ++cur; if (cur == 3) cur = 0;
    }
    asm volatile("s_waitcnt vmcnt(0)" ::: "memory");
    __builtin_amdgcn_s_barrier();
    compute(NKT - 1, cur);

    // ---- epilogue A: bias + activations + cell update + fragment-linear h store ----
    const int ll = lane & 15, lh = lane >> 4;
    const int colg = jb * 32 + wc * 16 + ll;
    float bsv[4];
    #pragma unroll
    for (int g = 0; g < 4; ++g) bsv[g] = bs[g * NA + colg];

    u16* htile = Hout + ((size_t)(mb * 16 + jb)) * 4096;
    const int ksub = wc * 2 + (ll >> 3);
    const int e = ll & 7;

    #pragma unroll
    for (int fm = 0; fm < 4; ++fm) {
        const int mf = wr * 4 + fm;
        #pragma unroll
        for (int q = 0; q < 4; ++q) {
            const int rloc = mf * 16 + lh * 4 + q;
            const size_t m = (size_t)mb * 128 + rloc;
            float gi = acc[fm][0][q] + bsv[0];
            float gf = acc[fm][1][q] + bsv[1];
            float gg = acc[fm][2][q] + bsv[2];
            float go = acc[fm][3][q] + bsv[3];
            float cv = c[m * NA + colg];
            float iv = sigf(gi), fv = sigf(gf);
            float gv = tanh_fast(gg), ov = sigf(go);
            float cn = fv * cv + iv * gv;
            float hn = ov * tanh_fast(cn);
            c[m * NA + colg] = cn;
            const int lanep = (lh * 4 + q) + 16 * ksub;
            htile[(mf * 64 + lanep) * 8 + e] = __builtin_bit_cast(u16, (f16)hn);
        }
    }

    // ---- epilogue B: cross-wave reduce of out_{t-1} strip (16 cols) ----
    if (do_out) {
        if (wc == 1) {
            float* P = (float*)(smem + wr * 4096);
            #pragma unroll
            for (int fm = 0; fm < 4; ++fm)
                #pragma unroll
                for (int q = 0; q < 4; ++q)
                    P[(fm * 16 + lh * 4 + q) * 16 + ll] = acc_o[fm][q];
        }
        __syncthreads();
        if (wc == 0) {
            const float* P = (const float*)(smem + wr * 4096);
            const float bo = b_out[jb * 16 + ll];
            #pragma unroll
            for (int fm = 0; fm < 4; ++fm)
                #pragma unroll
                for (int q = 0; q < 4; ++q) {
                    const int rloc = wr * 64 + fm * 16 + lh * 4 + q;
                    float v = acc_o[fm][q] + P[(fm * 16 + lh * 4 + q) * 16 + ll] + bo;
                    out_prev[((size_t)mb * 128 + rloc) * NV + jb * 16 + ll] = v;
                }
        }
    }

    // ---- epilogue C: convert X[:, t+1, :] -> fragment-linear fp16 ----
    if (do_xconv && jb < 8) {
        const int r = tid >> 1, kh = tid & 1;
        const float* xsrc = X + ((size_t)(mb * 128 + r) * T_X + (t + 1)) * NV + jb * 32 + kh * 16;
        f32x4 xv[4];
        #pragma unroll
        for (int i = 0; i < 4; ++i) xv[i] = *(const f32x4*)(xsrc + i * 4);
        u16* xt = Xf_next + ((size_t)(mb * 8 + jb)) * 4096;
        const int mf = r >> 4;
        #pragma unroll
        for (int s = 0; s < 2; ++s) {
            f16x8 v;
            #pragma unroll
            for (int j = 0; j < 8; ++j) v[j] = (f16)xv[s * 2 + (j >> 2)][j & 3];
            const int lanep = (r & 15) + 16 * (kh * 2 + s);
            *(f16x8*)(xt + (mf * 64 + lanep) * 8) = v;
        }
    }
}

// ====================== final output projection (t=127 only) ======================
__global__ __launch_bounds__(256)
void out_proj(const u16* __restrict__ Hin, const u16* __restrict__ BO,
              const float* __restrict__ b_out, float* __restrict__ out)
{
    __shared__ char smem[24576];   // 2 x (A 8K | B 4K)

    const int id  = blockIdx.x;
    const int xcd = id & 7, g2 = id >> 3;
    const int nb  = g2 & 3;
    const int mb  = xcd + 8 * (g2 >> 2);

    const int tid = threadIdx.x, lane = tid & 63, wv = tid >> 6;
    const int wr = wv >> 1, wc = wv & 1;

    f32x4 acc[4][2];
    #pragma unroll
    for (int a = 0; a < 4; ++a) { acc[a][0] = (f32x4){0,0,0,0}; acc[a][1] = (f32x4){0,0,0,0}; }

    auto stage = [&](int kt, int buf) {
        char* base = smem + buf * 12288;
        const char* asrc = (const char*)(Hin + ((size_t)(mb * 16 + kt)) * 4096);
        GLOAD_LDS16(asrc + wv * 2048 + lane * 16,        base + wv * 2048);
        GLOAD_LDS16(asrc + wv * 2048 + 1024 + lane * 16, base + wv * 2048 + 1024);
        const char* bsrc = (const char*)(BO + ((size_t)(kt * 4 + nb)) * 2048);
        GLOAD_LDS16(bsrc + wv * 1024 + lane * 16, base + 8192 + wv * 1024);
    };
    auto compute = [&](int buf) {
        const char* base = smem + buf * 12288;
        f16x8 bfr[2];
        #pragma unroll
        for (int fq = 0; fq < 2; ++fq)
            bfr[fq] = *(const f16x8*)(base + 8192 + (((wc * 2 + fq) * 64 + lane) << 4));
        #pragma unroll
        for (int fm = 0; fm < 4; ++fm) {
            f16x8 af = *(const f16x8*)(base + (((wr * 4 + fm) * 64 + lane) << 4));
            #pragma unroll
            for (int fq = 0; fq < 2; ++fq)
                acc[fm][fq] = __builtin_amdgcn_mfma_f32_16x16x32_f16(af, bfr[fq], acc[fm][fq], 0, 0, 0);
        }
    };

    stage(0, 0);
    __syncthreads();
    for (int kt = 0; kt < 16; ++kt) {
        const int cur = kt & 1;
        if (kt + 1 < 16) stage(kt + 1, cur ^ 1);
        compute(cur);
        __syncthreads();
    }

    const int ll = lane & 15, lh = lane >> 4;
    float bov[2];
    #pragma unroll
    for (int fq = 0; fq < 2; ++fq) bov[fq] = b_out[nb * 64 + (wc * 2 + fq) * 16 + ll];

    #pragma unroll
    for (int fm = 0; fm < 4; ++fm)
        #pragma unroll
        for (int fq = 0; fq < 2; ++fq)
            #pragma unroll
            for (int q = 0; q < 4; ++q) {
                const int row = mb * 128 + wr * 64 + fm * 16 + lh * 4 + q;
                const int col = nb * 64 + (wc * 2 + fq) * 16 + ll;
                out[(size_t)row * NV + col] = acc[fm][fq][q] + bov[fq];
            }
}

// ============================ host =============================
extern "C" void kernel_launch(void* const* d_in, const int* in_sizes, int n_in,
                              void* d_out, int out_size, void* d_ws, size_t ws_size,
                              hipStream_t stream) {
    const float* X     = (const float*)d_in[0];
    const float* a0    = (const float*)d_in[1];
    const float* c0    = (const float*)d_in[2];
    const float* W_ih  = (const float*)d_in[3];
    const float* W_hh  = (const float*)d_in[4];
    const float* b_ih  = (const float*)d_in[5];
    const float* b_hh  = (const float*)d_in[6];
    const float* W_out = (const float*)d_in[7];
    const float* b_out = (const float*)d_in[8];
    float* out = (float*)d_out;

    char* w = (char*)d_ws;
    u16*   Ha   = (u16*)(w);                                   // 4 MB
    u16*   Hb   = (u16*)(w + ((size_t)4 << 20));               // 4 MB
    float* cbf  = (float*)(w + ((size_t)8 << 20));             // 8 MB
    u16*   BG   = (u16*)(w + ((size_t)16 << 20));              // 3 MB
    u16*   BOs  = (u16*)(w + ((size_t)19 << 20));              // 256 KB
    u16*   BOo  = (u16*)(w + ((size_t)19 << 20) + 262144);     // 256 KB
    float* bsv  = (float*)(w + ((size_t)19 << 20) + 524288);   // 8 KB
    u16*   Xfa  = (u16*)(w + ((size_t)20 << 20));              // 2 MB
    u16*   Xfb  = (u16*)(w + ((size_t)22 << 20));              // 2 MB

    prep<<<8192, 256, 0, stream>>>(X, a0, c0, W_ih, W_hh, b_ih, b_hh, W_out,
                                   Ha, cbf, BG, BOs, BOo, bsv, Xfa);

    for (int t = 0; t < T_X; ++t) {
        const u16* hi = (t & 1) ? Hb : Ha;
        u16*       ho = (t & 1) ? Ha : Hb;
        const u16* xc = (t & 1) ? Xfb : Xfa;
        u16*       xn = (t & 1) ? Xfa : Xfb;
        float* outp = out + (size_t)(t > 0 ? t - 1 : 0) * M_DIM * NV;
        step_fused<<<512, 256, 0, stream>>>(X, xc, xn, hi, ho, cbf, BG, BOs, bsv, b_out,
                                            outp, t, t > 0 ? 1 : 0, t < T_X - 1 ? 1 : 0);
    }
    // final out for t=127 (h in Ha after odd t=127)
    out_proj<<<128, 256, 0, stream>>>(Ha, BOo, b_out, out + (size_t)(T_X - 1) * M_DIM * NV);
}